// Round 8
// baseline (773.571 us; speedup 1.0000x reference)
//
#include <hip/hip_runtime.h>
#include <math.h>

// Problem constants (from reference)
#define BATCH 64
#define TDIM 512
#define FEAT 2048
#define HID 1024
#define KDIM 512
#define MROWS (BATCH * TDIM)  // 32768 flat feats rows

typedef __attribute__((ext_vector_type(8))) short short8;
typedef __attribute__((ext_vector_type(4))) float floatx4;

// global -> LDS direct DMA, 16B per lane; LDS dest is wave-uniform base,
// lane i lands at base + i*16. Global source IS per-lane.
#define GLL16(g, l)                                                     \
    __builtin_amdgcn_global_load_lds(                                   \
        (const __attribute__((address_space(1))) void*)(g),             \
        (__attribute__((address_space(3))) void*)(l), 16, 0, 0)

// ---------------------------------------------------------------------------
// f32 -> bf16 (round-to-nearest-even)
// ---------------------------------------------------------------------------
__device__ __forceinline__ unsigned short f2bf(float x) {
    unsigned int u = __float_as_uint(x);
    u += 0x7FFFu + ((u >> 16) & 1u);
    return (unsigned short)(u >> 16);
}

// ---------------------------------------------------------------------------
// Device-scope sense-reversing grid barrier (G16 mechanism: agent-scope
// atomics with acquire/release; NO cooperative launch -> graph-capture safe).
// cnt returns to 0 after each use; gen is monotonic -> replay-safe as long
// as cnt starts 0 (k_init zeroes it each invocation; ws is re-poisoned).
// Release chain: each arriver's ACQ_REL fetch_add releases its block's
// writes; last arriver's RELEASE gen-bump carries them; waiters ACQUIRE gen.
// 40ms timeout: a co-residency failure yields a wrong answer (detectable),
// not a container-killing hang.
// ---------------------------------------------------------------------------
__device__ __forceinline__ void gbar(unsigned* cnt, unsigned* gen, int nblk) {
    __syncthreads();
    __threadfence();  // agent fence: flush this block's writes
    if (threadIdx.x == 0) {
        unsigned g = __hip_atomic_load(gen, __ATOMIC_ACQUIRE,
                                       __HIP_MEMORY_SCOPE_AGENT);
        unsigned a = __hip_atomic_fetch_add(cnt, 1u, __ATOMIC_ACQ_REL,
                                            __HIP_MEMORY_SCOPE_AGENT);
        if (a == (unsigned)(nblk - 1)) {
            __hip_atomic_store(cnt, 0u, __ATOMIC_RELAXED,
                               __HIP_MEMORY_SCOPE_AGENT);
            __hip_atomic_fetch_add(gen, 1u, __ATOMIC_RELEASE,
                                   __HIP_MEMORY_SCOPE_AGENT);
        } else {
            long long t0 = (long long)clock64();
            while (__hip_atomic_load(gen, __ATOMIC_ACQUIRE,
                                     __HIP_MEMORY_SCOPE_AGENT) == g) {
                __builtin_amdgcn_s_sleep(8);
                if ((long long)clock64() - t0 > 100000000LL) break;  // ~40ms
            }
        }
    }
    __syncthreads();
    __threadfence();
}

__global__ __launch_bounds__(64) void k_init(unsigned* __restrict__ bar) {
    if (threadIdx.x < 16) bar[threadIdx.x] = 0u;
}

// ---------------------------------------------------------------------------
// mega: whole pipeline, ONE plain launch. Grid 256 x 512thr, 84 KB LDS ->
// hard 1 block/CU (capacity co-residency for the atomic barrier).
//  P0: U f32->bf16 + Whb(GEMV)            ~8 us
//  P1: round-2 GEMM VERBATIM (164 us measured = m97-structure ceiling):
//      M=128 x N=512(all K), BK=64, reg-staged A (f32 read ONCE), GLL16 B,
//      XOR-swizzled LDS (0 conflicts), fused tanh/dot(w) -> energies.
//  P3: per-block redundant softmax (4 blocks/batch each redo the 512-wide
//      softmax locally; tq==0 writes weights) + pool its T-quarter -> pool4
//  P4: reduce 4 partials -> attn_feats
// Staging: whb in weights region (dead after P1); energies in attn region
// (dead after P3). 3 grid barriers total.
// ---------------------------------------------------------------------------
__global__ __launch_bounds__(512) void mega(
    const float* __restrict__ feats, const float* __restrict__ U,
    const float* __restrict__ hidden, const float* __restrict__ W,
    const float* __restrict__ bias, const float* __restrict__ wvec,
    unsigned short* __restrict__ uB, float* __restrict__ pool4,
    unsigned* __restrict__ bar,
    float* __restrict__ whb, float* __restrict__ energies,
    float* __restrict__ weights_out, float* __restrict__ attn_out) {
    __shared__ __align__(16) unsigned short As[128 * 64];  // 16 KB
    __shared__ __align__(16) unsigned short Bs[512 * 64];  // 64 KB
    __shared__ float sums[4][128];                         // 2 KB
    __shared__ float sm[512];                              // 2 KB

    const int tid  = threadIdx.x;
    const int bx   = blockIdx.x;
    const int wave = tid >> 6;
    const int lane = tid & 63;
    unsigned* cnt = bar;
    unsigned* gen = bar + 1;

    // ---- P0: U convert + Whb ---------------------------------------------
    {
        const int i2 = (bx * 512 + tid) * 2;  // 262144 float4 total
        #pragma unroll
        for (int r = 0; r < 2; ++r) {
            float4 v = ((const float4*)U)[i2 + r];
            ushort4 o;
            o.x = f2bf(v.x); o.y = f2bf(v.y); o.z = f2bf(v.z); o.w = f2bf(v.w);
            ((ushort4*)uB)[i2 + r] = o;
        }
        const int gw = bx * 8 + wave;  // 2048 waves x 16 outputs = 32768
        for (int o = gw * 16; o < gw * 16 + 16; ++o) {
            const int b = o >> 9, k = o & 511;
            const float* hrow = hidden + (size_t)b * HID;
            const float* wrow = W + (size_t)k * HID;
            float acc = 0.f;
            #pragma unroll 4
            for (int h = lane; h < HID; h += 64) acc += hrow[h] * wrow[h];
            #pragma unroll
            for (int off = 32; off > 0; off >>= 1) acc += __shfl_down(acc, off, 64);
            if (lane == 0) whb[o] = acc + bias[k];
        }
    }
    gbar(cnt, gen, 256);

    // ---- P1: GEMM (round-2 k2n body, verbatim) ---------------------------
    {
        const int row0 = bx * 128;
        const int wm = wave >> 2;            // 0..1 (M)
        const int wn = wave & 3;             // 0..3 (N)
        const int col = lane & 15, quad = lane >> 4;

        const int sr = tid >> 3;                  // row of slot tid (0..63)
        const int sc = (tid & 7) ^ (sr & 7);      // swizzled chunk
        const float* gA = feats + (size_t)(row0 + sr) * FEAT + sc * 8;
        unsigned short* lA0 = As + tid * 8;
        unsigned short* lA1 = As + (tid + 512) * 8;

        const int bq = (lane & 7) ^ ((lane >> 3) & 7);
        const int br = wave * 8 + (lane >> 3);
        const unsigned short* gBp[8];
        unsigned short* lB[8];
        #pragma unroll
        for (int g = 0; g < 8; ++g) {
            gBp[g] = uB + (size_t)(g * 64 + br) * FEAT + bq * 8;
            lB[g]  = Bs + (g * 512 + wave * 64) * 8;
        }

        floatx4 acc[4][8];
        #pragma unroll
        for (int i = 0; i < 4; ++i)
            #pragma unroll
            for (int j = 0; j < 8; ++j) acc[i][j] = (floatx4){0.f, 0.f, 0.f, 0.f};

        float4 a0 = *(const float4*)(gA);
        float4 a1 = *(const float4*)(gA + 4);
        float4 a2 = *(const float4*)(gA + (size_t)64 * FEAT);
        float4 a3 = *(const float4*)(gA + (size_t)64 * FEAT + 4);
        gA += 64;

        for (int f0 = 0; f0 < FEAT; f0 += 64) {
            #pragma unroll
            for (int g = 0; g < 8; ++g) { GLL16(gBp[g], lB[g]); gBp[g] += 64; }
            short8 w0, w1;
            w0[0] = f2bf(a0.x); w0[1] = f2bf(a0.y); w0[2] = f2bf(a0.z); w0[3] = f2bf(a0.w);
            w0[4] = f2bf(a1.x); w0[5] = f2bf(a1.y); w0[6] = f2bf(a1.z); w0[7] = f2bf(a1.w);
            w1[0] = f2bf(a2.x); w1[1] = f2bf(a2.y); w1[2] = f2bf(a2.z); w1[3] = f2bf(a2.w);
            w1[4] = f2bf(a3.x); w1[5] = f2bf(a3.y); w1[6] = f2bf(a3.z); w1[7] = f2bf(a3.w);
            *(short8*)lA0 = w0;
            *(short8*)lA1 = w1;
            __syncthreads();   // drains GLL16 + ds_writes: tile ready

            if (f0 + 64 < FEAT) {
                a0 = *(const float4*)(gA);
                a1 = *(const float4*)(gA + 4);
                a2 = *(const float4*)(gA + (size_t)64 * FEAT);
                a3 = *(const float4*)(gA + (size_t)64 * FEAT + 4);
                gA += 64;
            }

            #pragma unroll
            for (int kk = 0; kk < 2; ++kk) {
                const int sw = ((kk * 4 + quad) ^ (col & 7)) * 8;
                short8 af[4], bf[8];
                #pragma unroll
                for (int i = 0; i < 4; ++i)
                    af[i] = *(const short8*)&As[(wm * 64 + i * 16 + col) * 64 + sw];
                #pragma unroll
                for (int j = 0; j < 8; ++j)
                    bf[j] = *(const short8*)&Bs[(wn * 128 + j * 16 + col) * 64 + sw];
                #pragma unroll
                for (int i = 0; i < 4; ++i)
                    #pragma unroll
                    for (int j = 0; j < 8; ++j)
                        acc[i][j] = __builtin_amdgcn_mfma_f32_16x16x32_bf16(
                            af[i], bf[j], acc[i][j], 0, 0, 0);
            }
            __syncthreads();
        }

        // Epilogue. C/D layout: col = lane&15 (k-dim), row = quad*4 + reg (m).
        const int b = row0 >> 9;
        float wk[8], hk[8];
        #pragma unroll
        for (int j = 0; j < 8; ++j) {
            int k = wn * 128 + j * 16 + col;
            wk[j] = wvec[k];
            hk[j] = whb[b * KDIM + k];
        }
        #pragma unroll
        for (int i = 0; i < 4; ++i) {
            #pragma unroll
            for (int r = 0; r < 4; ++r) {
                float s = 0.f;
                #pragma unroll
                for (int j = 0; j < 8; ++j)
                    s += tanhf(acc[i][j][r] + hk[j]) * wk[j];
                #pragma unroll
                for (int off = 8; off > 0; off >>= 1)
                    s += __shfl_down(s, off, 16);
                if (col == 0)
                    sums[wn][wm * 64 + i * 16 + quad * 4 + r] = s;
            }
        }
        __syncthreads();
        if (tid < 128)
            energies[row0 + tid] =
                sums[0][tid] + sums[1][tid] + sums[2][tid] + sums[3][tid];
    }
    gbar(cnt, gen, 256);

    // ---- P3: per-block softmax (redundant x4) + pool T-quarter -----------
    {
        const int b = bx >> 2, tq = bx & 3, t0 = tq * 128;
        float* sred = &sums[0][0];  // 512-float scratch (dead As region? no:
                                    // sums is its own buffer, dead after P1)
        const float e = energies[b * TDIM + tid];
        sred[tid] = e;
        __syncthreads();
        #pragma unroll
        for (int s = 256; s > 0; s >>= 1) {
            if (tid < s) sred[tid] = fmaxf(sred[tid], sred[tid + s]);
            __syncthreads();
        }
        const float m = sred[0];
        __syncthreads();
        const float ex = __expf(e - m);
        sred[tid] = ex;
        __syncthreads();
        #pragma unroll
        for (int s = 256; s > 0; s >>= 1) {
            if (tid < s) sred[tid] += sred[tid + s];
            __syncthreads();
        }
        const float inv = 1.f / sred[0];
        sm[tid] = ex * inv;                       // full weights for batch b
        __syncthreads();
        if (tq == 0) weights_out[b * TDIM + tid] = sm[tid];

        const int f4 = tid * 4;
        const float* fp = feats + ((size_t)b * TDIM + t0) * FEAT + f4;
        float ax = 0.f, ay = 0.f, az = 0.f, aw = 0.f;
        #pragma unroll 4
        for (int t = 0; t < 128; ++t) {
            float4 v = *(const float4*)(fp + (size_t)t * FEAT);
            float w = sm[t0 + t];
            ax += v.x * w; ay += v.y * w; az += v.z * w; aw += v.w * w;
        }
        float4 o = {ax, ay, az, aw};
        *(float4*)(pool4 + ((size_t)tq * BATCH + b) * FEAT + f4) = o;
    }
    gbar(cnt, gen, 256);

    // ---- P4: reduce 4 partials -> attn_out -------------------------------
    {
        const int idx = bx * 512 + tid;  // 131072 = B*FEAT
        attn_out[idx] = pool4[idx] + pool4[BATCH * FEAT + idx] +
                        pool4[2 * BATCH * FEAT + idx] + pool4[3 * BATCH * FEAT + idx];
    }
}

// ---------------------------------------------------------------------------
// Fallback-path kernels (tiny ws): f32 pipeline
// ---------------------------------------------------------------------------
#define BM 128
#define BN 128
#define BF 16
#define LDSPAD 4

__global__ __launch_bounds__(256) void k1_whb(const float* __restrict__ hidden,
                                              const float* __restrict__ W,
                                              const float* __restrict__ bias,
                                              float* __restrict__ whb) {
    int b = blockIdx.y;
    int k = blockIdx.x * 4 + (threadIdx.x >> 6);
    int lane = threadIdx.x & 63;
    const float* hrow = hidden + (size_t)b * HID;
    const float* wrow = W + (size_t)k * HID;
    float acc = 0.f;
    #pragma unroll 4
    for (int h = lane; h < HID; h += 64) acc += hrow[h] * wrow[h];
    #pragma unroll
    for (int off = 32; off > 0; off >>= 1) acc += __shfl_down(acc, off, 64);
    if (lane == 0) whb[b * KDIM + k] = acc + bias[k];
}

__global__ __launch_bounds__(256) void k2_energy(const float* __restrict__ feats,
                                                 const float* __restrict__ U,
                                                 const float* __restrict__ whb,
                                                 const float* __restrict__ wvec,
                                                 float* __restrict__ partial) {
    __shared__ __align__(16) float As[BF][BM + LDSPAD];
    __shared__ __align__(16) float Us[BF][BN + LDSPAD];

    const int row0 = blockIdx.x * BM;
    const int k0   = blockIdx.y * BN;
    const int tid  = threadIdx.x;
    const int tx   = tid & 15;
    const int ty   = tid >> 4;

    float acc[8][8];
    #pragma unroll
    for (int i = 0; i < 8; ++i)
        #pragma unroll
        for (int j = 0; j < 8; ++j) acc[i][j] = 0.f;

    for (int f0 = 0; f0 < FEAT; f0 += BF) {
        #pragma unroll
        for (int l = 0; l < 2; ++l) {
            int li = tid + l * 256;
            int r  = li >> 2;
            int c4 = (li & 3) * 4;
            float4 av = *(const float4*)(feats + (size_t)(row0 + r) * FEAT + f0 + c4);
            float4 uv = *(const float4*)(U     + (size_t)(k0   + r) * FEAT + f0 + c4);
            As[c4 + 0][r] = av.x; As[c4 + 1][r] = av.y;
            As[c4 + 2][r] = av.z; As[c4 + 3][r] = av.w;
            Us[c4 + 0][r] = uv.x; Us[c4 + 1][r] = uv.y;
            Us[c4 + 2][r] = uv.z; Us[c4 + 3][r] = uv.w;
        }
        __syncthreads();
        #pragma unroll
        for (int kf = 0; kf < BF; ++kf) {
            float4 a0 = *(const float4*)&As[kf][ty * 8];
            float4 a1 = *(const float4*)&As[kf][ty * 8 + 4];
            float4 u0 = *(const float4*)&Us[kf][tx * 8];
            float4 u1 = *(const float4*)&Us[kf][tx * 8 + 4];
            float a[8] = {a0.x, a0.y, a0.z, a0.w, a1.x, a1.y, a1.z, a1.w};
            float u[8] = {u0.x, u0.y, u0.z, u0.w, u1.x, u1.y, u1.z, u1.w};
            #pragma unroll
            for (int i = 0; i < 8; ++i)
                #pragma unroll
                for (int j = 0; j < 8; ++j) acc[i][j] += a[i] * u[j];
        }
        __syncthreads();
    }

    const int b = row0 >> 9;
    float psum[8];
    #pragma unroll
    for (int i = 0; i < 8; ++i) {
        float s = 0.f;
        #pragma unroll
        for (int j = 0; j < 8; ++j) {
            int k = k0 + tx * 8 + j;
            s += tanhf(acc[i][j] + whb[b * KDIM + k]) * wvec[k];
        }
        psum[i] = s;
    }
    #pragma unroll
    for (int off = 8; off > 0; off >>= 1)
        #pragma unroll
        for (int i = 0; i < 8; ++i) psum[i] += __shfl_down(psum[i], off, 16);

    if (tx == 0) {
        int c = blockIdx.y;
        #pragma unroll
        for (int i = 0; i < 8; ++i)
            partial[c * MROWS + row0 + ty * 8 + i] = psum[i];
    }
}

__global__ __launch_bounds__(512) void k3_softmax(const float* __restrict__ partial,
                                                  float* __restrict__ wout) {
    int b = blockIdx.x;
    int t = threadIdx.x;
    float e = 0.f;
    #pragma unroll
    for (int c = 0; c < 4; ++c) e += partial[c * MROWS + b * TDIM + t];

    __shared__ float sm[512];
    sm[t] = e;
    __syncthreads();
    #pragma unroll
    for (int s = 256; s > 0; s >>= 1) {
        if (t < s) sm[t] = fmaxf(sm[t], sm[t + s]);
        __syncthreads();
    }
    float m = sm[0];
    __syncthreads();
    float ex = __expf(e - m);
    sm[t] = ex;
    __syncthreads();
    #pragma unroll
    for (int s = 256; s > 0; s >>= 1) {
        if (t < s) sm[t] += sm[t + s];
        __syncthreads();
    }
    float inv = 1.f / sm[0];
    wout[b * TDIM + t] = ex * inv;
}

__global__ __launch_bounds__(256) void k4_direct(const float* __restrict__ feats,
                                                 const float* __restrict__ weights,
                                                 float* __restrict__ out) {
    int b = blockIdx.y;
    int f4 = (blockIdx.x * 256 + threadIdx.x) * 4;
    __shared__ float wsm[TDIM];
    wsm[threadIdx.x]       = weights[b * TDIM + threadIdx.x];
    wsm[threadIdx.x + 256] = weights[b * TDIM + 256 + threadIdx.x];
    __syncthreads();

    const float* fp = feats + (size_t)b * TDIM * FEAT + f4;
    float ax = 0.f, ay = 0.f, az = 0.f, aw = 0.f;
    for (int t = 0; t < TDIM; ++t) {
        float4 v = *(const float4*)(fp + (size_t)t * FEAT);
        float w = wsm[t];
        ax += v.x * w; ay += v.y * w; az += v.z * w; aw += v.w * w;
    }
    float4 o = {ax, ay, az, aw};
    *(float4*)(out + (size_t)b * FEAT + f4) = o;
}

// ---------------------------------------------------------------------------
// Launch. d_out: [0, B*FEAT) attn_feats, [B*FEAT, +B*T) weights.
// Staging inside d_out: Whb in weights region (dead after mega P1);
// energies in attn region (dead after P3). d_ws: bf16 U (2 MiB) + pool
// partials (2 MiB) + barrier counters (64 B). Plain launches only
// (graph-capture safe); k_init zeroes the barrier each invocation.
// ---------------------------------------------------------------------------
extern "C" void kernel_launch(void* const* d_in, const int* in_sizes, int n_in,
                              void* d_out, int out_size, void* d_ws, size_t ws_size,
                              hipStream_t stream) {
    const float* hidden = (const float*)d_in[0];
    const float* feats  = (const float*)d_in[1];
    const float* W      = (const float*)d_in[2];
    const float* U      = (const float*)d_in[3];
    const float* bias   = (const float*)d_in[4];
    const float* wvec   = (const float*)d_in[5];

    float* out         = (float*)d_out;
    float* attn_out    = out;
    float* weights_out = out + (size_t)BATCH * FEAT;
    float* whb         = weights_out;  // staged (dead after P1)
    float* energies    = attn_out;     // staged (dead after P3)

    const size_t uBytes    = (size_t)KDIM * FEAT * sizeof(unsigned short);  // 2 MiB
    const size_t poolBytes = (size_t)4 * BATCH * FEAT * sizeof(float);      // 2 MiB
    const bool fast = ws_size >= uBytes + poolBytes + 64;

    if (fast) {
        unsigned short* uB = (unsigned short*)d_ws;
        float* pool4 = (float*)((char*)d_ws + uBytes);
        unsigned* bar = (unsigned*)((char*)d_ws + uBytes + poolBytes);
        k_init<<<dim3(1), 64, 0, stream>>>(bar);
        mega<<<dim3(256), 512, 0, stream>>>(feats, U, hidden, W, bias, wvec,
                                            uB, pool4, bar, whb, energies,
                                            weights_out, attn_out);
    } else {
        float* partial = attn_out;
        k1_whb<<<dim3(KDIM / 4, BATCH), 256, 0, stream>>>(hidden, W, bias, whb);
        k2_energy<<<dim3(MROWS / 128, KDIM / 128), 256, 0, stream>>>(
            feats, U, whb, wvec, partial);
        k3_softmax<<<dim3(BATCH), 512, 0, stream>>>(partial, weights_out);
        k4_direct<<<dim3(FEAT / 1024, BATCH), 256, 0, stream>>>(
            feats, weights_out, attn_out);
    }
}